// Round 1
// 521.151 us; speedup vs baseline: 1.0564x; 1.0564x over previous
//
#include <hip/hip_runtime.h>
#include <hip/hip_bf16.h>
#include <math.h>

#define LSEQ  1024
#define CIN   16
#define COUT  16
#define BATCH 4
#define TILE  16
#define NT    13          // MFMAs per strip: K = 26 combos * 16 ci = 416 = 13*32
#define CSTR  48          // bytes per (row,col) LDS cell: 16 ci * 2B padded to 48 (16B-aligned; 2-way = free)
#define RSTR  (20 * CSTR) // 960 B per LDS row

#define WFRAG_BYTES (NT * 64 * 8 * 2)                       // 13312, 16B-aligned
#define PROBS_ELEMS ((size_t)BATCH * CIN * LSEQ * LSEQ)     // 67.1M ushorts
#define WS_NEEDED   (WFRAG_BYTES + PROBS_ELEMS * 2)

typedef __attribute__((ext_vector_type(8))) short short8;
typedef __attribute__((ext_vector_type(4))) float f32x4;
typedef __attribute__((ext_vector_type(4))) int   i32x4;

static __device__ __forceinline__ unsigned f2bf_u(float f) {
    unsigned u = __builtin_bit_cast(unsigned, f);
    return (u + 0x7fff + ((u >> 16) & 1)) >> 16;   // RNE, returns in low 16
}
static __device__ __forceinline__ unsigned short f2bf(float f) { return (unsigned short)f2bf_u(f); }

// ===========================================================================
// PASS 1: causal softmax -> bf16 probs, CI-INTERLEAVED layout [b][row][col][ci]
// (32 B per (row,col) cell) so pass 2 can stage with contiguous 16 B loads.
// Block = (b,row): 4 waves x 4 ci rows each (proven per-row wave code),
// bf16 into LDS [ci][1024], then transpose write-out of cols 0..row as
// contiguous 16 B chunks. Last block instead builds MFMA A-fragments.
// ===========================================================================
__global__ __launch_bounds__(256) void softmax_probs_kernel(
    const float* __restrict__ scores,
    const float* __restrict__ weight,
    ushort* __restrict__ wfrag,
    ushort* __restrict__ probs)
{
    const int tid = threadIdx.x;

    if (blockIdx.x == BATCH * LSEQ) {
        // Weight A-fragment prep: A[m=co][k], k = combo*16+ci, combo=kh*5+kw.
        // Lane layout (16x16x32): m=lane&15, k_local=(lane>>4)*8+j.
        for (int slot = tid; slot < NT * 64; slot += 256) {
            const int t = slot >> 6, lane = slot & 63;
            const int co = lane & 15, q = lane >> 4;
            const int ci0 = (q & 1) * 8, cb = q >> 1;
            const int c = 2 * t + cb;
            ushort* dst = wfrag + (size_t)slot * 8;
            #pragma unroll
            for (int jj = 0; jj < 8; ++jj) {
                float wv = (c < 25) ? weight[co * (CIN * 25) + (ci0 + jj) * 25 + c] : 0.f;
                dst[jj] = f2bf(wv);
            }
        }
        return;
    }

    __shared__ ushort sm[CIN * LSEQ];                 // 32 KiB, [ci][col]

    const int bi   = blockIdx.x;                      // b*L + row
    const int b    = bi >> 10;
    const int row  = bi & (LSEQ - 1);
    const int wv   = tid >> 6;
    const int lane = tid & 63;

    #pragma unroll
    for (int m = 0; m < 4; ++m) {
        const int ci = wv * 4 + m;
        const float* rowp = scores + ((size_t)(b * CIN + ci) * LSEQ + row) * LSEQ;

        float e[16];
        #pragma unroll
        for (int c = 0; c < 4; ++c) {
            const int j0 = c * 256 + lane * 4;
            float4 v = make_float4(0.f, 0.f, 0.f, 0.f);
            if (c * 256 <= row) v = *(const float4*)(rowp + j0);
            e[c*4+0] = (j0 + 0 <= row) ? __expf(v.x) : 0.f;
            e[c*4+1] = (j0 + 1 <= row) ? __expf(v.y) : 0.f;
            e[c*4+2] = (j0 + 2 <= row) ? __expf(v.z) : 0.f;
            e[c*4+3] = (j0 + 3 <= row) ? __expf(v.w) : 0.f;
        }
        float s = 0.f;
        #pragma unroll
        for (int t = 0; t < 16; ++t) s += e[t];
        #pragma unroll
        for (int off = 32; off > 0; off >>= 1) s += __shfl_xor(s, off, 64);
        const float rinv = 1.0f / s;

        ushort* smrow = sm + ci * LSEQ;
        #pragma unroll
        for (int c = 0; c < 4; ++c) {
            if (c * 256 <= row) {
                const int j0 = c * 256 + lane * 4;
                uint2 pk;
                pk.x = f2bf_u(e[c*4+0] * rinv) | (f2bf_u(e[c*4+1] * rinv) << 16);
                pk.y = f2bf_u(e[c*4+2] * rinv) | (f2bf_u(e[c*4+3] * rinv) << 16);
                *(uint2*)(smrow + j0) = pk;           // linear 8 B writes, conflict-free
            }
        }
    }
    __syncthreads();

    // Transpose write-out: chunk = (col, ci-half) -> 16 B contiguous store.
    // Only cols <= row are ever read by pass 2 (masked there), so stop at row.
    ushort* prow = probs + ((size_t)b * LSEQ + row) * (LSEQ * CIN);
    const int nch = 2 * (row + 1);
    for (int chunk = tid; chunk < nch; chunk += 256) {
        const int col = chunk >> 1;
        const int h   = chunk & 1;
        i32x4 pk;
        #pragma unroll
        for (int k = 0; k < 4; ++k) {
            unsigned lo = sm[(h * 8 + 2 * k    ) * LSEQ + col];
            unsigned hi = sm[(h * 8 + 2 * k + 1) * LSEQ + col];
            pk[k] = (int)(lo | (hi << 16));
        }
        *(i32x4*)(prow + (size_t)col * CIN + h * 8) = pk;
    }
}

// ===========================================================================
// PASS 2: implicit-GEMM conv via bf16 MFMA. Staging from ci-interleaved probs:
// one contiguous 16 B global load + one ds_write_b128 per half-cell (800/block
// vs 6400 scalar 2 B gathers before). Compute path unchanged (proven):
// LDS [20r][20c][16ci] bf16, cell stride 48 B; 4 strips x 13 (b128 + MFMA).
// ===========================================================================
__global__ __launch_bounds__(256) void conv_mfma2_kernel(
    const ushort* __restrict__ probs,
    const float* __restrict__ bias,
    const ushort* __restrict__ wfrag,
    float* __restrict__ out)
{
    const int jt = blockIdx.x, it = blockIdx.y, b = blockIdx.z;
    const int j0 = jt * TILE, i0 = it * TILE;
    const int tid = threadIdx.x;

    if (jt > it) {  // tile fully above diagonal: pure zero-store
        #pragma unroll
        for (int vv = 0; vv < 4; ++vv) {
            int e  = vv * 256 + tid;
            int co = e >> 6, il = (e >> 2) & 15, jq = e & 3;
            *(float4*)(out + ((size_t)(b * COUT + co) * LSEQ + i0 + il) * LSEQ + j0 + jq * 4)
                = make_float4(0.f, 0.f, 0.f, 0.f);
        }
        return;
    }

    const int lane = tid & 63;
    const int w    = tid >> 6;
    const int n    = lane & 15;
    const int q    = lane >> 4;

    short8 af[NT];
    #pragma unroll
    for (int t = 0; t < NT; ++t)
        af[t] = *(const short8*)(wfrag + (size_t)(t * 64 + lane) * 8);

    float bs[4];
    #pragma unroll
    for (int r = 0; r < 4; ++r) bs[r] = bias[q * 4 + r];

    int addr[NT];
    {
        const int cb  = q >> 1;
        const int cio = (q & 1) * 16;
        #pragma unroll
        for (int t = 0; t < NT; ++t) {
            int c = 2 * t + cb;
            if (c >= 25) addr[t] = 0;
            else {
                int kh = c / 5, kw = c - kh * 5;
                addr[t] = (kh * 20 + (n + kw)) * CSTR + cio + w * (4 * RSTR);
            }
        }
    }

    __shared__ ushort ptile[20 * 20 * 24];   // 19200 B (cells of 24 ushorts)

    // Stage: 800 tasks = 400 cells x 2 ci-halves; one 16 B load + one b128 store.
    const ushort* pb = probs + (size_t)b * (LSEQ * LSEQ * CIN);
    #pragma unroll
    for (int u = 0; u < 4; ++u) {
        const int e = u * 256 + tid;
        if (e < 800) {
            const int half = e & 1, cell = e >> 1;
            const int rr = cell / 20, cc = cell - rr * 20;
            const int row = i0 - 2 + rr;
            const int col = j0 - 2 + cc;
            const bool ok = (row >= 0) && (row < LSEQ) && (col >= 0) && (col < LSEQ) && (col <= row);
            i32x4 pk = {0, 0, 0, 0};
            if (ok)
                pk = *(const i32x4*)(pb + ((size_t)row * LSEQ + col) * CIN + half * 8);
            *(i32x4*)((char*)ptile + cell * CSTR + half * 16) = pk;
        }
    }
    __syncthreads();

    #pragma unroll
    for (int s = 0; s < 4; ++s) {
        f32x4 acc = {0.f, 0.f, 0.f, 0.f};
        #pragma unroll
        for (int t = 0; t < NT; ++t) {
            short8 bf = *(const short8*)((const char*)ptile + addr[t] + s * RSTR);
            acc = __builtin_amdgcn_mfma_f32_16x16x32_bf16(af[t], bf, acc, 0, 0, 0);
        }
        const int i = i0 + w * 4 + s;
        const int j = j0 + n;
        #pragma unroll
        for (int r = 0; r < 4; ++r) {
            const int co = q * 4 + r;
            out[((size_t)(b * COUT + co) * LSEQ + i) * LSEQ + j] = (j <= i) ? (acc[r] + bs[r]) : 0.f;
        }
    }
}

// ===========================================================================
// FALLBACK (round-2 proven path) if ws_size < ~128 MiB.
// ===========================================================================
__global__ __launch_bounds__(256) void stats_fb_kernel(const float* __restrict__ scores,
                                                       float* __restrict__ rowinv)
{
    const int w   = blockIdx.x;
    const int row = w & (LSEQ - 1);
    const int tid = threadIdx.x;
    const int j0  = tid * 4;
    float4 v = make_float4(0.f, 0.f, 0.f, 0.f);
    if (j0 <= row) v = *(const float4*)(scores + (size_t)w * LSEQ + j0);
    float s = 0.f;
    s += (j0 + 0 <= row) ? __expf(v.x) : 0.f;
    s += (j0 + 1 <= row) ? __expf(v.y) : 0.f;
    s += (j0 + 2 <= row) ? __expf(v.z) : 0.f;
    s += (j0 + 3 <= row) ? __expf(v.w) : 0.f;
    #pragma unroll
    for (int off = 32; off > 0; off >>= 1) s += __shfl_xor(s, off, 64);
    __shared__ float part[4];
    if ((tid & 63) == 0) part[tid >> 6] = s;
    __syncthreads();
    if (tid == 0) rowinv[w] = 1.0f / (part[0] + part[1] + part[2] + part[3]);
}

__global__ void wprep_fb_kernel(const float* __restrict__ weight, ushort* __restrict__ wfrag)
{
    const int lane = threadIdx.x;
    const int co   = lane & 15;
    const int q    = lane >> 4;
    const int ci0  = (q & 1) * 8;
    const int cb   = q >> 1;
    for (int t = 0; t < NT; ++t) {
        const int c = 2 * t + cb;
        ushort* dst = wfrag + (size_t)(t * 64 + lane) * 8;
        #pragma unroll
        for (int jj = 0; jj < 8; ++jj) {
            float wv = (c < 25) ? weight[co * (CIN * 25) + (ci0 + jj) * 25 + c] : 0.f;
            dst[jj] = f2bf(wv);
        }
    }
}

__global__ __launch_bounds__(256) void conv_fb_kernel(
    const float* __restrict__ scores,
    const float* __restrict__ bias,
    const float* __restrict__ rowinv,
    const ushort* __restrict__ wfrag,
    float* __restrict__ out)
{
    const int jt = blockIdx.x, it = blockIdx.y, b = blockIdx.z;
    const int j0 = jt * TILE, i0 = it * TILE;
    const int tid = threadIdx.x;

    if (jt > it) {
        #pragma unroll
        for (int vv = 0; vv < 4; ++vv) {
            int e  = vv * 256 + tid;
            int co = e >> 6, il = (e >> 2) & 15, jq = e & 3;
            *(float4*)(out + ((size_t)(b * COUT + co) * LSEQ + i0 + il) * LSEQ + j0 + jq * 4)
                = make_float4(0.f, 0.f, 0.f, 0.f);
        }
        return;
    }

    const int lane = tid & 63;
    const int w    = tid >> 6;
    const int n    = lane & 15;
    const int q    = lane >> 4;

    short8 af[NT];
    #pragma unroll
    for (int t = 0; t < NT; ++t)
        af[t] = *(const short8*)(wfrag + (size_t)(t * 64 + lane) * 8);

    float bs[4];
    #pragma unroll
    for (int r = 0; r < 4; ++r) bs[r] = bias[q * 4 + r];

    int addr[NT];
    {
        const int cb  = q >> 1;
        const int cio = (q & 1) * 16;
        #pragma unroll
        for (int t = 0; t < NT; ++t) {
            int c = 2 * t + cb;
            if (c >= 25) addr[t] = 0;
            else {
                int kh = c / 5, kw = c - kh * 5;
                addr[t] = (kh * 20 + (n + kw)) * CSTR + cio + w * (4 * RSTR);
            }
        }
    }

    __shared__ ushort ptile[20 * 20 * 24];

    for (int u = 0; u < 8; ++u) {
        int e = u * 256 + tid;
        if (e < 1920) {
            int ci  = e / 120;
            int rem = e - ci * 120;
            int rr  = rem / 6;
            int cq  = rem - rr * 6;
            int row  = i0 - 2 + rr;
            int gcol = j0 - 4 + cq * 4;
            bool rok = (row >= 0) && (row < LSEQ);
            float rinv = 0.f;
            float4 v = make_float4(0.f, 0.f, 0.f, 0.f);
            if (rok) {
                int rid = (b * CIN + ci) * LSEQ + row;
                rinv = rowinv[rid];
                if (gcol >= 0 && gcol <= LSEQ - 4 && gcol <= row)
                    v = *(const float4*)(scores + (size_t)rid * LSEQ + gcol);
            }
            float pv[4] = {v.x, v.y, v.z, v.w};
            #pragma unroll
            for (int l = 0; l < 4; ++l) {
                int col = gcol + l;
                int cc  = cq * 4 - 2 + l;
                bool ok = rok && col >= 0 && col < LSEQ && col <= row;
                float p = ok ? __expf(pv[l]) * rinv : 0.f;
                if (cc >= 0 && cc < 20)
                    ptile[(rr * 20 + cc) * 24 + ci] = f2bf(p);
            }
        }
    }
    __syncthreads();

    #pragma unroll
    for (int s = 0; s < 4; ++s) {
        f32x4 acc = {0.f, 0.f, 0.f, 0.f};
        #pragma unroll
        for (int t = 0; t < NT; ++t) {
            short8 bf = *(const short8*)((const char*)ptile + addr[t] + s * RSTR);
            acc = __builtin_amdgcn_mfma_f32_16x16x32_bf16(af[t], bf, acc, 0, 0, 0);
        }
        const int i = i0 + w * 4 + s;
        const int j = j0 + n;
        #pragma unroll
        for (int r = 0; r < 4; ++r) {
            const int co = q * 4 + r;
            out[((size_t)(b * COUT + co) * LSEQ + i) * LSEQ + j] = (j <= i) ? (acc[r] + bs[r]) : 0.f;
        }
    }
}

extern "C" void kernel_launch(void* const* d_in, const int* in_sizes, int n_in,
                              void* d_out, int out_size, void* d_ws, size_t ws_size,
                              hipStream_t stream) {
    const float* scores = (const float*)d_in[0];
    const float* weight = (const float*)d_in[1];
    const float* bias   = (const float*)d_in[2];
    float* out = (float*)d_out;

    if (ws_size >= WS_NEEDED) {
        ushort* wfrag = (ushort*)d_ws;
        ushort* probs = (ushort*)((char*)d_ws + WFRAG_BYTES);

        softmax_probs_kernel<<<BATCH * LSEQ + 1, 256, 0, stream>>>(
            scores, weight, wfrag, probs);

        dim3 g(LSEQ / TILE, LSEQ / TILE, BATCH);
        conv_mfma2_kernel<<<g, 256, 0, stream>>>(probs, bias, wfrag, out);
    } else {
        float*  rowinv = (float*)d_ws;
        ushort* wfrag  = (ushort*)((char*)d_ws + (size_t)BATCH * CIN * LSEQ * 4);

        stats_fb_kernel<<<BATCH * CIN * LSEQ, 256, 0, stream>>>(scores, rowinv);
        wprep_fb_kernel<<<1, 64, 0, stream>>>(weight, wfrag);

        dim3 g(LSEQ / TILE, LSEQ / TILE, BATCH);
        conv_fb_kernel<<<g, 256, 0, stream>>>(scores, bias, rowinv, wfrag, out);
    }
}